// Round 13
// baseline (7839.658 us; speedup 1.0000x reference)
//
#include <hip/hip_runtime.h>
#include <stdint.h>

#define NB 8
#define NN 8192
#define NP 2048
#define NSAMP 32
#define NC 64
#define NBK 512

typedef unsigned long long u64;

// ---------------------------------------------------------------------------
// prep: weight transposes for coalesced per-k reads in the fused MLP kernel.
// ---------------------------------------------------------------------------
__global__ __launch_bounds__(256) void prep_kernel(
    const float* __restrict__ w1, const float* __restrict__ w2,
    const float* __restrict__ w3, float* __restrict__ w1t,
    float* __restrict__ w2t, float* __restrict__ w3t)
{
    int j = blockIdx.x * 256 + threadIdx.x;
    if (j < 64*67) { int o = j / 67, k = j % 67; w1t[k*64 + o] = w1[j]; }
    int j2 = j - 64*67;
    if (j2 >= 0 && j2 < 64*64) { int o = j2 >> 6, k = j2 & 63; w2t[k*64 + o] = w2[j2]; }
    int j3 = j2 - 64*64;
    if (j3 >= 0 && j3 < 128*64) { int o = j3 >> 6, k = j3 & 63; w3t[k*128 + o] = w3[j3]; }
}

// ---------------------------------------------------------------------------
// FPS v7: bucket-pruned. 512 threads = 512 spatial buckets (8x8x8 grid).
// Points bucket-sorted into LDS float4 (x,y,z,dist); thread t owns bucket t.
// Per iteration:
//   - prune: skip bucket iff conservative lb(far,bucket) > cached bucket max
//     (then min(dist,d)=dist for all members -> bit-exact no-op, cache valid)
//   - active buckets: rescan members, update dist, recompute (max,oid,slot)
//   - global argmax: packed u64 (valbits<<26)|((8191-oid)<<13)|slot,
//     wave shfl-max + 8 wave slots (parity dbuf) + redundant merge.
//     Ordering = (val desc, oid asc) == reference first-occurrence argmax.
// Distance math bit-identical to verified r7-r12: separate-op f32,
// contract(off): d = ((dx*dx + dy*dy) + dz*dz); dist = fminf(dist, d).
// Bound safety: t = dfc - RB - 1e-6 (abs margin >> 5ulp), lb = t^2*(1-1e-6)
// <= every f32-rounded d to bucket members. Equality -> active (conservative).
// ---------------------------------------------------------------------------
__global__ __launch_bounds__(512, 1) void fps_kernel(
    const float* __restrict__ xyz, int* __restrict__ fps_idx,
    float* __restrict__ out_newxyz)
{
#pragma clang fp contract(off)
    __shared__ __align__(16) float4 pt4[NN];          // 128 KiB (x,y,z,dist)
    __shared__ unsigned short oid16[NN];              //  16 KiB
    __shared__ unsigned int   hist[NBK];              //   2 KiB (also cursor)
    __shared__ unsigned short bstart[NBK + 1];
    __shared__ u64 wslot[2][8];

    const int b = blockIdx.x;
    const int t = threadIdx.x;
    const int lane = t & 63;
    const int w = t >> 6;
    const float* base = xyz + (size_t)b * NN * 3;

    // ---- setup: bucket histogram ----
    hist[t] = 0;
    __syncthreads();
    #pragma unroll 4
    for (int i = t * 16; i < t * 16 + 16; i++) {
        float x = base[i*3+0], y = base[i*3+1], z = base[i*3+2];
        int ix = min(7, (int)(x * 8.0f));
        int iy = min(7, (int)(y * 8.0f));
        int iz = min(7, (int)(z * 8.0f));
        atomicAdd(&hist[(ix << 6) | (iy << 3) | iz], 1u);
    }
    __syncthreads();
    if (t == 0) {                       // exclusive scan (one-time, ~2us)
        unsigned int u = 0;
        for (int j = 0; j < NBK; j++) { bstart[j] = (unsigned short)u; u += hist[j]; }
        bstart[NBK] = (unsigned short)u;
    }
    __syncthreads();
    hist[t] = bstart[t];                // cursor
    __syncthreads();
    // ---- scatter (unstable within bucket; tie-breaks are explicit) ----
    #pragma unroll 4
    for (int i = t * 16; i < t * 16 + 16; i++) {
        float x = base[i*3+0], y = base[i*3+1], z = base[i*3+2];
        int ix = min(7, (int)(x * 8.0f));
        int iy = min(7, (int)(y * 8.0f));
        int iz = min(7, (int)(z * 8.0f));
        int pos = (int)atomicAdd(&hist[(ix << 6) | (iy << 3) | iz], 1u);
        pt4[pos] = (float4){ x, y, z, 1e10f };
        oid16[pos] = (unsigned short)i;
    }
    __syncthreads();

    // ---- per-thread bucket state ----
    const int s0 = bstart[t], s1 = bstart[t + 1];
    const float bcx = (float)((t >> 6) & 7) * 0.125f + 0.0625f;
    const float bcy = (float)((t >> 3) & 7) * 0.125f + 0.0625f;
    const float bcz = (float)(t & 7)        * 0.125f + 0.0625f;
    const float RB = 0.108254f;         // >= cell half-diagonal (0.10825318)

    u64 mypack = (s0 < s1) ? ((u64)__float_as_uint(1e10f) << 26) : 0ULL;

    float fx = base[0], fy = base[1], fz = base[2];
    int farOid = 0;

    for (int k = 0; k < NP; k++) {
        if (t == 0) {
            fps_idx[b * NP + k] = farOid;
            out_newxyz[((size_t)b * NP + k) * 3 + 0] = fx;
            out_newxyz[((size_t)b * NP + k) * 3 + 1] = fy;
            out_newxyz[((size_t)b * NP + k) * 3 + 2] = fz;
        }

        // prune bound (conservative; any rounding slack absorbed by margins)
        float dx = fx - bcx, dy = fy - bcy, dz = fz - bcz;
        float dfc = sqrtf((dx*dx + dy*dy) + dz*dz);
        float tt = dfc - RB - 1e-6f;
        float lb = (tt > 0.0f) ? tt * tt * (1.0f - 1e-6f) : 0.0f;
        float bmax = __uint_as_float((unsigned int)(mypack >> 26));

        if (lb <= bmax && s0 < s1) {
            // active: update members, recompute (max, min-oid, slot)
            float bestv = -1.0f; int bestoid = 1 << 30; int bestslot = 0;
            for (int s = s0; s < s1; s++) {
                float4 v = pt4[s];
                float ddx = v.x - fx, ddy = v.y - fy, ddz = v.z - fz;
                float d = (ddx*ddx + ddy*ddy) + ddz*ddz;   // contract(off)
                float nd = fminf(v.w, d);
                pt4[s].w = nd;
                int o = oid16[s];
                bool better = (nd > bestv) || (nd == bestv && o < bestoid);
                if (better) { bestv = nd; bestoid = o; bestslot = s; }
            }
            mypack = ((u64)__float_as_uint(bestv) << 26)
                   | ((u64)(8191 - bestoid) << 13) | (u64)bestslot;
        }

        // wave reduce (u64 max == lexicographic (val desc, oid asc))
        u64 m = mypack;
        #pragma unroll
        for (int off = 1; off < 64; off <<= 1) {
            u64 o = __shfl_xor(m, off);
            if (o > m) m = o;
        }
        if (lane == 0) wslot[k & 1][w] = m;
        __syncthreads();

        // redundant 8-way merge on every thread
        u64 g = wslot[k & 1][0];
        #pragma unroll
        for (int j = 1; j < 8; j++) { u64 o = wslot[k & 1][j]; if (o > g) g = o; }
        int slot = (int)(g & 8191);
        farOid = 8191 - (int)((g >> 13) & 8191);
        float4 fc = pt4[slot];          // coords immutable -> race-free
        fx = fc.x; fy = fc.y; fz = fc.z;
    }
}

// ---------------------------------------------------------------------------
// Fused ball-query + group + 3-layer MLP + max-pool. One wave per query.
// VERIFIED rounds 7-12 (absmax 0.0). d2: pp/qq separate-op, dot FMA chain,
// d2 separate-op, strict < 0.04f. DO NOT TOUCH.
// ---------------------------------------------------------------------------
__global__ __launch_bounds__(64) void fused_kernel(
    const float* __restrict__ xyz, const float* __restrict__ features,
    const int* __restrict__ fps_idx,
    const float* __restrict__ w1t, const float* __restrict__ b1,
    const float* __restrict__ w2t, const float* __restrict__ b2,
    const float* __restrict__ w3t, const float* __restrict__ b3,
    float* __restrict__ out_feat)
{
#pragma clang fp contract(off)
    constexpr int XP = 36;
    __shared__ __align__(16) float Xs[67 * XP];
    __shared__ __align__(16) float Hs[64 * XP];
    __shared__ int ids[NSAMP];

    const int q = blockIdx.x;           // b*NP + s
    const int b = q >> 11, s = q & (NP - 1);
    const int lane = threadIdx.x;
    const float* base = xyz + (size_t)b * NN * 3;

    // ---- ball query (one wave) ----
    int qi = fps_idx[q];
    float qx = base[qi*3+0], qy = base[qi*3+1], qz = base[qi*3+2];
    float qq = (qx*qx + qy*qy) + qz*qz;              // separate-op (contract off)
    const float RR = 0.04f;                          // f32(0.2*0.2), strict <

    int have = 0, first = 0;
    for (int c = 0; c < NN / 64; c++) {
        int p = c * 64 + lane;
        float px = base[p*3+0], py = base[p*3+1], pz = base[p*3+2];
        float pp  = (px*px + py*py) + pz*pz;         // separate-op
        float dot = fmaf(qz, pz, fmaf(qy, py, qx*px));  // einsum FMA chain
        float d2  = (qq + pp) - 2.0f*dot;            // separate-op
        bool pred = d2 < RR;
        unsigned long long m = __ballot(pred);
        if (have == 0 && m) first = c * 64 + (int)__builtin_ctzll(m);
        if (pred) {
            int rank = have + (int)__popcll(m & ((1ULL << lane) - 1ULL));
            if (rank < NSAMP) ids[rank] = p;
        }
        have += (int)__popcll(m);
        if (have >= NSAMP) break;
    }
    if (lane < NSAMP && lane >= have) ids[lane] = first;
    __syncthreads();

    // ---- build X: rows 0..2 = grouped_xyz - center, rows 3..66 = features ----
    if (lane < NSAMP) {
        int id = ids[lane];
        Xs[0*XP + lane] = base[id*3+0] - qx;
        Xs[1*XP + lane] = base[id*3+1] - qy;
        Xs[2*XP + lane] = base[id*3+2] - qz;
    }
    {
        const float* frow = features + ((size_t)b * NC + lane) * NN;
        #pragma unroll
        for (int n0 = 0; n0 < NSAMP; n0 += 4) {
            float4 v;
            v.x = frow[ids[n0+0]];
            v.y = frow[ids[n0+1]];
            v.z = frow[ids[n0+2]];
            v.w = frow[ids[n0+3]];
            *(float4*)&Xs[(3 + lane) * XP + n0] = v;
        }
    }
    __syncthreads();

    float acc[32];
    // ---- layer 1: 67 -> 64 ----
    {
        float bias = b1[lane];
        #pragma unroll
        for (int n = 0; n < 32; n++) acc[n] = bias;
        for (int k = 0; k < 67; k++) {
            float w = w1t[k*64 + lane];
            const float4* xr = (const float4*)&Xs[k * XP];
            #pragma unroll
            for (int n4 = 0; n4 < 8; n4++) {
                float4 xv = xr[n4];
                acc[n4*4+0] = fmaf(w, xv.x, acc[n4*4+0]);
                acc[n4*4+1] = fmaf(w, xv.y, acc[n4*4+1]);
                acc[n4*4+2] = fmaf(w, xv.z, acc[n4*4+2]);
                acc[n4*4+3] = fmaf(w, xv.w, acc[n4*4+3]);
            }
        }
        #pragma unroll
        for (int n0 = 0; n0 < 32; n0 += 4) {
            float4 v;
            v.x = fmaxf(acc[n0+0], 0.f); v.y = fmaxf(acc[n0+1], 0.f);
            v.z = fmaxf(acc[n0+2], 0.f); v.w = fmaxf(acc[n0+3], 0.f);
            *(float4*)&Hs[lane * XP + n0] = v;
        }
    }
    __syncthreads();
    // ---- layer 2: 64 -> 64 (output into Xs rows 0..63) ----
    {
        float bias = b2[lane];
        #pragma unroll
        for (int n = 0; n < 32; n++) acc[n] = bias;
        for (int k = 0; k < 64; k++) {
            float w = w2t[k*64 + lane];
            const float4* xr = (const float4*)&Hs[k * XP];
            #pragma unroll
            for (int n4 = 0; n4 < 8; n4++) {
                float4 xv = xr[n4];
                acc[n4*4+0] = fmaf(w, xv.x, acc[n4*4+0]);
                acc[n4*4+1] = fmaf(w, xv.y, acc[n4*4+1]);
                acc[n4*4+2] = fmaf(w, xv.z, acc[n4*4+2]);
                acc[n4*4+3] = fmaf(w, xv.w, acc[n4*4+3]);
            }
        }
        __syncthreads();
        #pragma unroll
        for (int n0 = 0; n0 < 32; n0 += 4) {
            float4 v;
            v.x = fmaxf(acc[n0+0], 0.f); v.y = fmaxf(acc[n0+1], 0.f);
            v.z = fmaxf(acc[n0+2], 0.f); v.w = fmaxf(acc[n0+3], 0.f);
            *(float4*)&Xs[lane * XP + n0] = v;
        }
    }
    __syncthreads();
    // ---- layer 3: 64 -> 128 (2 ch/lane) + max-pool + relu ----
    {
        float accA[32], accB[32];
        float ba = b3[lane], bb = b3[lane + 64];
        #pragma unroll
        for (int n = 0; n < 32; n++) { accA[n] = ba; accB[n] = bb; }
        for (int k = 0; k < 64; k++) {
            float wa = w3t[k*128 + lane];
            float wb = w3t[k*128 + lane + 64];
            const float4* xr = (const float4*)&Xs[k * XP];
            #pragma unroll
            for (int n4 = 0; n4 < 8; n4++) {
                float4 xv = xr[n4];
                accA[n4*4+0] = fmaf(wa, xv.x, accA[n4*4+0]);
                accA[n4*4+1] = fmaf(wa, xv.y, accA[n4*4+1]);
                accA[n4*4+2] = fmaf(wa, xv.z, accA[n4*4+2]);
                accA[n4*4+3] = fmaf(wa, xv.w, accA[n4*4+3]);
                accB[n4*4+0] = fmaf(wb, xv.x, accB[n4*4+0]);
                accB[n4*4+1] = fmaf(wb, xv.y, accB[n4*4+1]);
                accB[n4*4+2] = fmaf(wb, xv.z, accB[n4*4+2]);
                accB[n4*4+3] = fmaf(wb, xv.w, accB[n4*4+3]);
            }
        }
        float mA = accA[0], mB = accB[0];
        #pragma unroll
        for (int n = 1; n < 32; n++) { mA = fmaxf(mA, accA[n]); mB = fmaxf(mB, accB[n]); }
        mA = fmaxf(mA, 0.f); mB = fmaxf(mB, 0.f);
        out_feat[((size_t)b*128 + lane)      * NP + s] = mA;
        out_feat[((size_t)b*128 + lane + 64) * NP + s] = mB;
    }
}

// ---------------------------------------------------------------------------
extern "C" void kernel_launch(void* const* d_in, const int* in_sizes, int n_in,
                              void* d_out, int out_size, void* d_ws, size_t ws_size,
                              hipStream_t stream)
{
    const float* xyz      = (const float*)d_in[0];
    const float* features = (const float*)d_in[1];
    const float* w1 = (const float*)d_in[2];
    const float* b1 = (const float*)d_in[3];
    const float* w2 = (const float*)d_in[4];
    const float* b2 = (const float*)d_in[5];
    const float* w3 = (const float*)d_in[6];
    const float* b3 = (const float*)d_in[7];

    float* out        = (float*)d_out;
    float* out_newxyz = out;                  // (8,2048,3) = 49152 floats
    float* out_feat   = out + NB * NP * 3;    // (8,128,2048)

    char* ws = (char*)d_ws;
    int*   fps_idx = (int*)(ws + 0);          // 16384 i32  -> 65536 B
    float* w1t     = (float*)(ws + 65536);    //  4288 f32
    float* w2t     = (float*)(ws + 82688);    //  4096 f32
    float* w3t     = (float*)(ws + 99072);    //  8192 f32

    prep_kernel<<<65, 256, 0, stream>>>(w1, w2, w3, w1t, w2t, w3t);
    fps_kernel<<<NB, 512, 0, stream>>>(xyz, fps_idx, out_newxyz);
    fused_kernel<<<NB * NP, 64, 0, stream>>>(xyz, features, fps_idx,
                                             w1t, b1, w2t, b2, w3t, b3, out_feat);
}